// Round 17
// baseline (134.188 us; speedup 1.0000x reference)
//
#include <hip/hip_runtime.h>
#include <hip/hip_bf16.h>

typedef unsigned short u16;
typedef unsigned int u32;
typedef __bf16 bf16x8 __attribute__((ext_vector_type(8)));
typedef float f32x4 __attribute__((ext_vector_type(4)));
typedef float f32x16 __attribute__((ext_vector_type(16)));

#define DMODEL 1024
#define NH 16
#define DH 64
#define BB 2
#define TT 2048
#define MM 4096   // BB*TT
#define NQKV 3072
#define KVB 128   // attention key-tile

// Q pre-scale: Dh^-0.5 * log2(e) -> scores land in log2 domain (P = v_exp_f32 direct)
#define QSCALE 0.18033688011112042f

static __device__ __forceinline__ u16 f2bf(float f) {
  u32 u = __float_as_uint(f);
  u = (u + 0x7FFFu + ((u >> 16) & 1u)) >> 16;  // RNE
  return (u16)u;
}

static __device__ __forceinline__ u32 pk2bf(float a, float b) {
  u16 ua = __builtin_bit_cast(u16, (__bf16)a);
  u16 ub = __builtin_bit_cast(u16, (__bf16)b);
  return (u32)ua | ((u32)ub << 16);
}

static __device__ __forceinline__ float fexp2(float x) {
#if __has_builtin(__builtin_amdgcn_exp2f)
  return __builtin_amdgcn_exp2f(x);
#else
  float r; asm("v_exp_f32 %0, %1" : "=v"(r) : "v"(x)); return r;
#endif
}

static __device__ __forceinline__ float max3f(float a, float b, float c) {
  return fmaxf(fmaxf(a, b), c);  // fuses to v_max3_f32
}

static __device__ __forceinline__ float maxv16(const f32x16& v) {
  float t0 = max3f(v[0], v[1], v[2]);
  float t1 = max3f(v[3], v[4], v[5]);
  float t2 = max3f(v[6], v[7], v[8]);
  float t3 = max3f(v[9], v[10], v[11]);
  float t4 = max3f(v[12], v[13], v[14]);
  return fmaxf(max3f(t0, t1, t2), max3f(t3, t4, v[15]));
}

static __device__ __forceinline__ void gload16(const u16* g, u16* l) {
  __builtin_amdgcn_global_load_lds(
      (const __attribute__((address_space(1))) void*)g,
      (__attribute__((address_space(3))) void*)l, 16, 0, 0);
}

// Fused f32->bf16 convert: x | wqkv | wproj (dst regions contiguous in ws).
#define N4X  (MM * DMODEL / 4)
#define N4W  (NQKV * DMODEL / 4)
#define N4P  (DMODEL * DMODEL / 4)
__global__ __launch_bounds__(256) void cvt_all(const float* __restrict__ x,
                                               const float* __restrict__ wqkv,
                                               const float* __restrict__ wproj,
                                               u16* __restrict__ dst) {
  int i = blockIdx.x * 256 + threadIdx.x;
  const float* src;
  int j = i;
  if (i < N4X) {
    src = x;
  } else if (i < N4X + N4W) {
    src = wqkv; j = i - N4X;
  } else {
    src = wproj; j = i - (N4X + N4W);
  }
  float4 v = reinterpret_cast<const float4*>(src)[j];
  ushort4 o;
  o.x = f2bf(v.x); o.y = f2bf(v.y); o.z = f2bf(v.z); o.w = f2bf(v.w);
  reinterpret_cast<ushort4*>(dst)[i] = o;
}

// ---------- GEMM: 128x128 tile, K=1024, counted-vmcnt pipeline (r12 form) ----------
static __device__ __forceinline__ void gemm_stage(
    const u16* __restrict__ A, const u16* __restrict__ B, u16* As, u16* Bs,
    int r0, int o0, int r1, int o1, int c0, int c1, int kcol) {
  gload16(A + (size_t)r0 * DMODEL + kcol + o0, As + c0 * 8);
  gload16(A + (size_t)r1 * DMODEL + kcol + o1, As + c1 * 8);
  gload16(B + (size_t)r0 * DMODEL + kcol + o0, Bs + c0 * 8);
  gload16(B + (size_t)r1 * DMODEL + kcol + o1, Bs + c1 * 8);
}

static __device__ __forceinline__ void gemm128_mainloop(
    const u16* __restrict__ Abase, const u16* __restrict__ Bbase,
    u16* As, u16* Bs, f32x4 (&acc)[4][4]) {
  const int tid = threadIdx.x;
  const int lane = tid & 63;
  const int w = tid >> 6;
  const int rowg = lane >> 4, col = lane & 15;
  const int wm = w >> 1, wn = w & 1;
  const int c0 = tid, c1 = tid + 256;
  const int r0 = c0 >> 2, o0 = (c0 & 3) * 8;
  const int r1 = c1 >> 2, o1 = (c1 & 3) * 8;

  gemm_stage(Abase, Bbase, As, Bs, r0, o0, r1, o1, c0, c1, 0);

#define GCOMP(AS, BS)                                                                 \
  {                                                                                   \
    bf16x8 af[4], bfr[4];                                                             \
    _Pragma("unroll") for (int i = 0; i < 4; ++i)                                     \
      af[i] = *reinterpret_cast<const bf16x8*>((AS) + (wm * 64 + i * 16 + col) * 32 + rowg * 8); \
    _Pragma("unroll") for (int j = 0; j < 4; ++j)                                     \
      bfr[j] = *reinterpret_cast<const bf16x8*>((BS) + (wn * 64 + j * 16 + col) * 32 + rowg * 8); \
    _Pragma("unroll") for (int i = 0; i < 4; ++i)                                     \
      _Pragma("unroll") for (int j = 0; j < 4; ++j)                                   \
        acc[i][j] = __builtin_amdgcn_mfma_f32_16x16x32_bf16(af[i], bfr[j], acc[i][j], 0, 0, 0); \
  }

  for (int kt = 0; kt < DMODEL / 32; kt += 2) {
    gemm_stage(Abase, Bbase, As + 4096, Bs + 4096, r0, o0, r1, o1, c0, c1,
               ((kt + 1) & (DMODEL / 32 - 1)) * 32);
    asm volatile("s_waitcnt vmcnt(4)" ::: "memory");
    __builtin_amdgcn_s_barrier();
    __builtin_amdgcn_sched_barrier(0);
    GCOMP(As, Bs);
    __builtin_amdgcn_sched_barrier(0);
    __builtin_amdgcn_s_barrier();
    gemm_stage(Abase, Bbase, As, Bs, r0, o0, r1, o1, c0, c1,
               ((kt + 2) & (DMODEL / 32 - 1)) * 32);
    asm volatile("s_waitcnt vmcnt(4)" ::: "memory");
    __builtin_amdgcn_s_barrier();
    __builtin_amdgcn_sched_barrier(0);
    GCOMP(As + 4096, Bs + 4096);
    __builtin_amdgcn_sched_barrier(0);
    __builtin_amdgcn_s_barrier();
  }
#undef GCOMP
}

// QKV projection: C[m,n] = x[m,:] . Wqkv[n,:]; scatter to q/k/vt, q pre-scaled.
// XCD slab swizzle (T1): implicit XCD = blockIdx.x % 8 (gridX=24 ≡ 0 mod 8). Remap each
// XCD's 96 blocks to a compact 12x8 (col x row) slab -> A-panels 8/XCD, B-panels 12/XCD.
__global__ __launch_bounds__(256, 3) void qkv_gemm(
    const u16* __restrict__ xb, const u16* __restrict__ wb,
    u16* __restrict__ qb, u16* __restrict__ kb, u16* __restrict__ vtb) {
  __shared__ u16 As[2 * 128 * 32];
  __shared__ u16 Bs[2 * 128 * 32];
  const int xcd = blockIdx.x & 7;
  const int j = (blockIdx.x >> 3) * 32 + blockIdx.y;   // 0..95 within XCD
  const int bx = (j % 12) + (xcd & 1) * 12;            // col tile 0..23
  const int by = (j / 12) + (xcd >> 1) * 8;            // row tile 0..31
  f32x4 acc[4][4];
#pragma unroll
  for (int i = 0; i < 4; ++i)
#pragma unroll
    for (int jj = 0; jj < 4; ++jj) acc[i][jj] = (f32x4){0.f, 0.f, 0.f, 0.f};
  gemm128_mainloop(xb + (size_t)by * 128 * DMODEL,
                   wb + (size_t)bx * 128 * DMODEL, As, Bs, acc);
  const int lane = threadIdx.x & 63, w = threadIdx.x >> 6;
  const int rowg = lane >> 4, col = lane & 15, wm = w >> 1, wn = w & 1;
#pragma unroll
  for (int i = 0; i < 4; ++i) {
#pragma unroll
    for (int jj = 0; jj < 4; ++jj) {
#pragma unroll
      for (int r = 0; r < 4; ++r) {
        int m = by * 128 + wm * 64 + i * 16 + rowg * 4 + r;
        int n = bx * 128 + wn * 64 + jj * 16 + col;
        int b = m >> 11, t = m & (TT - 1);
        int s = n >> 10, h = (n >> 6) & 15, d = n & 63;
        int bh = b * NH + h;
        float v = acc[i][jj][r];
        if (s == 0)      qb[((size_t)bh * TT + t) * DH + d] = f2bf(v * QSCALE);
        else if (s == 1) kb[((size_t)bh * TT + t) * DH + d] = f2bf(v);
        else             vtb[((size_t)bh * DH + d) * TT + t] = f2bf(v);
      }
    }
  }
}

// Output projection: out[m,n] = ob[m,:] . Wproj[n,:], f32 out.
// XCD slab swizzle: gridX=8 -> XCD = blockIdx.x; each XCD's 32 blocks -> 8x4 slab.
__global__ __launch_bounds__(256, 3) void proj_gemm(
    const u16* __restrict__ ab, const u16* __restrict__ wb, float* __restrict__ out) {
  __shared__ u16 As[2 * 128 * 32];
  __shared__ u16 Bs[2 * 128 * 32];
  const int xcd = blockIdx.x & 7;
  const int bx = blockIdx.y & 7;                       // col tile 0..7
  const int by = (blockIdx.y >> 3) + xcd * 4;          // row tile 0..31
  f32x4 acc[4][4];
#pragma unroll
  for (int i = 0; i < 4; ++i)
#pragma unroll
    for (int j = 0; j < 4; ++j) acc[i][j] = (f32x4){0.f, 0.f, 0.f, 0.f};
  gemm128_mainloop(ab + (size_t)by * 128 * DMODEL,
                   wb + (size_t)bx * 128 * DMODEL, As, Bs, acc);
  const int lane = threadIdx.x & 63, w = threadIdx.x >> 6;
  const int rowg = lane >> 4, col = lane & 15, wm = w >> 1, wn = w & 1;
#pragma unroll
  for (int i = 0; i < 4; ++i) {
#pragma unroll
    for (int j = 0; j < 4; ++j) {
#pragma unroll
      for (int r = 0; r < 4; ++r) {
        int m = by * 128 + wm * 64 + i * 16 + rowg * 4 + r;
        int n = bx * 128 + wn * 64 + j * 16 + col;
        out[(size_t)m * DMODEL + n] = acc[i][j][r];
      }
    }
  }
}

// ---------- Flash attention: r15 form (best measured): 4 waves x 32 q, 32x32x16, ----------
// ---------- in-reg P, KVB=128, counted vmcnt(8), bh-major grid (K/V L2-local).   ----------
static __device__ __forceinline__ void attn_stage(
    const u16* __restrict__ kbase, const u16* __restrict__ vbase,
    int kt, u16* KsSel, u16* VsSel, int tid) {
#pragma unroll
  for (int p = 0; p < 4; ++p) {
    int c = p * 256 + tid;
    int row = c >> 3;
    int bI = (c & 7) * 16;
    gload16(kbase + kt * (KVB * DH) + row * DH + ((bI ^ ((row & 7) << 4)) >> 1), KsSel + c * 8);
  }
#pragma unroll
  for (int p = 0; p < 4; ++p) {
    int c = p * 256 + tid;
    int d = c >> 4;
    int bI = (c & 15) * 16;
    gload16(vbase + (size_t)d * TT + kt * KVB + ((bI ^ ((d & 7) << 4)) >> 1), VsSel + c * 8);
  }
}

__global__ __launch_bounds__(256, 2) void attn_kernel(
    const u16* __restrict__ qb, const u16* __restrict__ kb,
    const u16* __restrict__ vtb, const unsigned char* __restrict__ mask,
    u16* __restrict__ ob) {
  __shared__ u16 SM[2][2][KVB * DH];
  __shared__ unsigned char maskb[TT];
  __shared__ u32 mflag;

  const int tid = threadIdx.x;
  const int lane = tid & 63, w = tid >> 6;
  const int col = lane & 31, h = lane >> 5;
  const int bh = blockIdx.x, qt = blockIdx.y;   // bh-major: XCD = bh % 8
  const int b = bh >> 4;

  if (tid == 0) mflag = 0;
  __syncthreads();

  {
    const u32* mg = reinterpret_cast<const u32*>(mask + (size_t)b * TT);
    u32 m0 = mg[tid * 2], m1 = mg[tid * 2 + 1];
    *reinterpret_cast<u32*>(maskb + tid * 8) = m0;
    *reinterpret_cast<u32*>(maskb + tid * 8 + 4) = m1;
    if (m0 | m1) atomicOr(&mflag, 1u << (tid >> 4));
  }

  const int qrow0 = qt * 128 + w * 32;
  const u16* qptr = qb + ((size_t)bh * TT + qrow0) * DH;
  bf16x8 aq[4];
#pragma unroll
  for (int dstep = 0; dstep < 4; ++dstep)
    aq[dstep] = *reinterpret_cast<const bf16x8*>(qptr + col * DH + dstep * 16 + h * 8);

  f32x16 acc[2];
#pragma unroll
  for (int df = 0; df < 2; ++df)
#pragma unroll
    for (int r = 0; r < 16; ++r) acc[df][r] = 0.f;
  float m_run = -1e30f, l_run = 0.f;

  const u16* kbase = kb + (size_t)bh * TT * DH;
  const u16* vbase = vtb + (size_t)bh * DH * TT;

  attn_stage(kbase, vbase, 0, SM[0][0], SM[0][1], tid);
  __syncthreads();
  const u32 fm = mflag;

#define ATILE(T, KS, VS)                                                              \
  do {                                                                                \
    const int t_ = (T);                                                               \
    f32x16 sc[4];                                                                     \
    _Pragma("unroll") for (int kf = 0; kf < 4; ++kf)                                  \
      _Pragma("unroll") for (int r = 0; r < 16; ++r) sc[kf][r] = 0.f;                 \
    _Pragma("unroll") for (int dstep = 0; dstep < 4; ++dstep) {                       \
      bf16x8 ak[4];                                                                   \
      _Pragma("unroll") for (int kf = 0; kf < 4; ++kf) {                              \
        int row = kf * 32 + col;                                                      \
        ak[kf] = *reinterpret_cast<const bf16x8*>(                                    \
            (KS) + row * DH + (((dstep * 32 + h * 16) ^ ((row & 7) << 4)) >> 1));     \
      }                                                                               \
      _Pragma("unroll") for (int kf = 0; kf < 4; ++kf)                                \
        sc[kf] = __builtin_amdgcn_mfma_f32_32x32x16_bf16(ak[kf], aq[dstep], sc[kf], 0, 0, 0); \
    }                                                                                 \
    if (fm & (1u << t_)) {                                                            \
      _Pragma("unroll") for (int kf = 0; kf < 4; ++kf)                                \
        _Pragma("unroll") for (int r = 0; r < 16; ++r) {                              \
          int key = kf * 32 + (r & 3) + 8 * (r >> 2) + 4 * h;                         \
          sc[kf][r] += maskb[t_ * KVB + key] ? -1e30f : 0.f;                          \
        }                                                                             \
    }                                                                                 \
    u32 P2[4][8];                                                                     \
    {                                                                                 \
      float mk0 = maxv16(sc[0]), mk1 = maxv16(sc[1]);                                 \
      float mk2 = maxv16(sc[2]), mk3 = maxv16(sc[3]);                                 \
      float mx = fmaxf(fmaxf(mk0, mk1), fmaxf(mk2, mk3));                             \
      mx = fmaxf(mx, __shfl_xor(mx, 32, 64));                                         \
      if (__any(mx > m_run + 8.0f)) {                                                 \
        float mn = fmaxf(m_run, mx);                                                  \
        float corr = fexp2(m_run - mn);                                               \
        m_run = mn;                                                                   \
        l_run *= corr;                                                                \
        _Pragma("unroll") for (int df = 0; df < 2; ++df)                              \
          _Pragma("unroll") for (int r = 0; r < 16; ++r) acc[df][r] *= corr;          \
      }                                                                               \
      const float mc = m_run;                                                         \
      float rs = 0.f;                                                                 \
      _Pragma("unroll") for (int kf = 0; kf < 4; ++kf) {                              \
        _Pragma("unroll") for (int i = 0; i < 8; ++i) {                               \
          float p0 = fexp2(sc[kf][2 * i] - mc);                                       \
          float p1 = fexp2(sc[kf][2 * i + 1] - mc);                                   \
          rs += p0 + p1;                                                              \
          P2[kf][i] = pk2bf(p0, p1);                                                  \
        }                                                                             \
      }                                                                               \
      rs += __shfl_xor(rs, 32, 64);                                                   \
      l_run += rs;                                                                    \
    }                                                                                 \
    __builtin_amdgcn_s_setprio(1);                                                    \
    _Pragma("unroll") for (int ksl = 0; ksl < 8; ++ksl) {                             \
      const int kf = ksl >> 1;                                                        \
      const int i0 = (ksl & 1) * 4;                                                   \
      u32 w0 = P2[kf][i0],     w2 = P2[kf][i0 + 2];                                   \
      u32 w1 = P2[kf][i0 + 1], w3 = P2[kf][i0 + 3];                                   \
      asm("v_permlane32_swap_b32 %0, %1" : "+v"(w0), "+v"(w2));                       \
      asm("v_permlane32_swap_b32 %0, %1" : "+v"(w1), "+v"(w3));                       \
      u32 bpw[4] = {w0, w1, w2, w3};                                                  \
      bf16x8 bp = __builtin_bit_cast(bf16x8, *reinterpret_cast<uint4*>(bpw));         \
      _Pragma("unroll") for (int df = 0; df < 2; ++df) {                              \
        int row = df * 32 + col;                                                      \
        bf16x8 av = *reinterpret_cast<const bf16x8*>(                                 \
            (VS) + row * KVB + (((ksl * 32 + h * 16) ^ ((row & 7) << 4)) >> 1));      \
        acc[df] = __builtin_amdgcn_mfma_f32_32x32x16_bf16(av, bp, acc[df], 0, 0, 0);  \
      }                                                                               \
    }                                                                                 \
    __builtin_amdgcn_s_setprio(0);                                                    \
  } while (0)

  for (int t = 0; t < TT / KVB; t += 2) {
    attn_stage(kbase, vbase, t + 1, SM[1][0], SM[1][1], tid);
    asm volatile("s_waitcnt vmcnt(8)" ::: "memory");
    __builtin_amdgcn_s_barrier();
    __builtin_amdgcn_sched_barrier(0);
    ATILE(t, SM[0][0], SM[0][1]);
    __builtin_amdgcn_sched_barrier(0);
    __builtin_amdgcn_s_barrier();
    attn_stage(kbase, vbase, (t + 2) & (TT / KVB - 1), SM[0][0], SM[0][1], tid);
    asm volatile("s_waitcnt vmcnt(8)" ::: "memory");
    __builtin_amdgcn_s_barrier();
    __builtin_amdgcn_sched_barrier(0);
    ATILE(t + 1, SM[1][0], SM[1][1]);
    __builtin_amdgcn_sched_barrier(0);
    __builtin_amdgcn_s_barrier();
  }
#undef ATILE

  asm volatile("s_waitcnt vmcnt(0)" ::: "memory");
  __builtin_amdgcn_s_barrier();

  u16* Ol = &SM[0][0][0];
  {
    float inv = 1.f / l_run;
    const int q = w * 32 + col;
    const int swzq = (q ^ (q >> 3)) & 7;
#pragma unroll
    for (int df = 0; df < 2; ++df) {
#pragma unroll
      for (int a = 0; a < 4; ++a) {
        uint2 pk;
        pk.x = pk2bf(acc[df][4 * a] * inv, acc[df][4 * a + 1] * inv);
        pk.y = pk2bf(acc[df][4 * a + 2] * inv, acc[df][4 * a + 3] * inv);
        int d2 = df * 64 + a * 16 + h * 8;
        int byte = q * 128 + (d2 ^ (swzq << 4));
        *reinterpret_cast<uint2*>(reinterpret_cast<char*>(Ol) + byte) = pk;
      }
    }
  }
  __syncthreads();
  {
    const int hh = bh & 15;
#pragma unroll
    for (int p = 0; p < 4; ++p) {
      int idx = p * 256 + tid;
      int q = idx >> 3, ch = idx & 7;
      int swzq = (q ^ (q >> 3)) & 7;
      uint4 v = *reinterpret_cast<const uint4*>(
          reinterpret_cast<const char*>(Ol) + q * 128 + ((ch * 16) ^ (swzq << 4)));
      size_t row = (size_t)(b * TT + qt * 128 + q);
      *reinterpret_cast<uint4*>(ob + row * DMODEL + hh * DH + ch * 8) = v;
    }
  }
}

extern "C" void kernel_launch(void* const* d_in, const int* in_sizes, int n_in,
                              void* d_out, int out_size, void* d_ws, size_t ws_size,
                              hipStream_t stream) {
  const float* x = (const float*)d_in[0];
  const unsigned char* mask = (const unsigned char*)d_in[1];
  const float* wqkv = (const float*)d_in[2];
  const float* wproj = (const float*)d_in[3];
  float* out = (float*)d_out;

  u16* xb     = (u16*)d_ws;
  u16* wqkvb  = xb    + (size_t)MM * DMODEL;
  u16* wprojb = wqkvb + (size_t)NQKV * DMODEL;
  u16* qb     = wprojb + (size_t)DMODEL * DMODEL;
  u16* kb     = qb + (size_t)MM * DMODEL;
  u16* vtb    = kb + (size_t)MM * DMODEL;
  u16* ob     = vtb + (size_t)MM * DMODEL;

  cvt_all<<<(N4X + N4W + N4P) / 256, 256, 0, stream>>>(x, wqkv, wproj, xb);
  qkv_gemm<<<dim3(NQKV / 128, MM / 128), 256, 0, stream>>>(xb, wqkvb, qb, kb, vtb);
  attn_kernel<<<dim3(BB * NH, TT / 128), 256, 0, stream>>>(qb, kb, vtb, mask, ob);
  proj_gemm<<<dim3(DMODEL / 128, MM / 128), 256, 0, stream>>>(ob, wprojb, out);
}

// Round 18
// 126.866 us; speedup vs baseline: 1.0577x; 1.0577x over previous
//
#include <hip/hip_runtime.h>
#include <hip/hip_bf16.h>

typedef unsigned short u16;
typedef unsigned int u32;
typedef __bf16 bf16x8 __attribute__((ext_vector_type(8)));
typedef float f32x4 __attribute__((ext_vector_type(4)));
typedef float f32x16 __attribute__((ext_vector_type(16)));

#define DMODEL 1024
#define NH 16
#define DH 64
#define BB 2
#define TT 2048
#define MM 4096   // BB*TT
#define NQKV 3072
#define KVB 128   // attention key-tile

// Q pre-scale: Dh^-0.5 * log2(e) -> scores land in log2 domain (P = v_exp_f32 direct)
#define QSCALE 0.18033688011112042f

static __device__ __forceinline__ u16 f2bf(float f) {
  u32 u = __float_as_uint(f);
  u = (u + 0x7FFFu + ((u >> 16) & 1u)) >> 16;  // RNE
  return (u16)u;
}

static __device__ __forceinline__ u32 pk2bf(float a, float b) {
  u16 ua = __builtin_bit_cast(u16, (__bf16)a);
  u16 ub = __builtin_bit_cast(u16, (__bf16)b);
  return (u32)ua | ((u32)ub << 16);
}

static __device__ __forceinline__ float fexp2(float x) {
#if __has_builtin(__builtin_amdgcn_exp2f)
  return __builtin_amdgcn_exp2f(x);
#else
  float r; asm("v_exp_f32 %0, %1" : "=v"(r) : "v"(x)); return r;
#endif
}

static __device__ __forceinline__ float max3f(float a, float b, float c) {
  return fmaxf(fmaxf(a, b), c);  // fuses to v_max3_f32
}

static __device__ __forceinline__ float maxv16(const f32x16& v) {
  float t0 = max3f(v[0], v[1], v[2]);
  float t1 = max3f(v[3], v[4], v[5]);
  float t2 = max3f(v[6], v[7], v[8]);
  float t3 = max3f(v[9], v[10], v[11]);
  float t4 = max3f(v[12], v[13], v[14]);
  return fmaxf(max3f(t0, t1, t2), max3f(t3, t4, v[15]));
}

static __device__ __forceinline__ void gload16(const u16* g, u16* l) {
  __builtin_amdgcn_global_load_lds(
      (const __attribute__((address_space(1))) void*)g,
      (__attribute__((address_space(3))) void*)l, 16, 0, 0);
}

// Fused f32->bf16 convert: x | wqkv | wproj (dst regions contiguous in ws).
#define N4X  (MM * DMODEL / 4)
#define N4W  (NQKV * DMODEL / 4)
#define N4P  (DMODEL * DMODEL / 4)
__global__ __launch_bounds__(256) void cvt_all(const float* __restrict__ x,
                                               const float* __restrict__ wqkv,
                                               const float* __restrict__ wproj,
                                               u16* __restrict__ dst) {
  int i = blockIdx.x * 256 + threadIdx.x;
  const float* src;
  int j = i;
  if (i < N4X) {
    src = x;
  } else if (i < N4X + N4W) {
    src = wqkv; j = i - N4X;
  } else {
    src = wproj; j = i - (N4X + N4W);
  }
  float4 v = reinterpret_cast<const float4*>(src)[j];
  ushort4 o;
  o.x = f2bf(v.x); o.y = f2bf(v.y); o.z = f2bf(v.z); o.w = f2bf(v.w);
  reinterpret_cast<ushort4*>(dst)[i] = o;
}

// ---------- GEMM: 128x128 tile, K=1024, counted-vmcnt pipeline (r12 form) ----------
static __device__ __forceinline__ void gemm_stage(
    const u16* __restrict__ A, const u16* __restrict__ B, u16* As, u16* Bs,
    int r0, int o0, int r1, int o1, int c0, int c1, int kcol) {
  gload16(A + (size_t)r0 * DMODEL + kcol + o0, As + c0 * 8);
  gload16(A + (size_t)r1 * DMODEL + kcol + o1, As + c1 * 8);
  gload16(B + (size_t)r0 * DMODEL + kcol + o0, Bs + c0 * 8);
  gload16(B + (size_t)r1 * DMODEL + kcol + o1, Bs + c1 * 8);
}

static __device__ __forceinline__ void gemm128_mainloop(
    const u16* __restrict__ Abase, const u16* __restrict__ Bbase,
    u16* As, u16* Bs, f32x4 (&acc)[4][4]) {
  const int tid = threadIdx.x;
  const int lane = tid & 63;
  const int w = tid >> 6;
  const int rowg = lane >> 4, col = lane & 15;
  const int wm = w >> 1, wn = w & 1;
  const int c0 = tid, c1 = tid + 256;
  const int r0 = c0 >> 2, o0 = (c0 & 3) * 8;
  const int r1 = c1 >> 2, o1 = (c1 & 3) * 8;

  gemm_stage(Abase, Bbase, As, Bs, r0, o0, r1, o1, c0, c1, 0);

#define GCOMP(AS, BS)                                                                 \
  {                                                                                   \
    bf16x8 af[4], bfr[4];                                                             \
    _Pragma("unroll") for (int i = 0; i < 4; ++i)                                     \
      af[i] = *reinterpret_cast<const bf16x8*>((AS) + (wm * 64 + i * 16 + col) * 32 + rowg * 8); \
    _Pragma("unroll") for (int j = 0; j < 4; ++j)                                     \
      bfr[j] = *reinterpret_cast<const bf16x8*>((BS) + (wn * 64 + j * 16 + col) * 32 + rowg * 8); \
    _Pragma("unroll") for (int i = 0; i < 4; ++i)                                     \
      _Pragma("unroll") for (int j = 0; j < 4; ++j)                                   \
        acc[i][j] = __builtin_amdgcn_mfma_f32_16x16x32_bf16(af[i], bfr[j], acc[i][j], 0, 0, 0); \
  }

  for (int kt = 0; kt < DMODEL / 32; kt += 2) {
    gemm_stage(Abase, Bbase, As + 4096, Bs + 4096, r0, o0, r1, o1, c0, c1,
               ((kt + 1) & (DMODEL / 32 - 1)) * 32);
    asm volatile("s_waitcnt vmcnt(4)" ::: "memory");
    __builtin_amdgcn_s_barrier();
    __builtin_amdgcn_sched_barrier(0);
    GCOMP(As, Bs);
    __builtin_amdgcn_sched_barrier(0);
    __builtin_amdgcn_s_barrier();
    gemm_stage(Abase, Bbase, As, Bs, r0, o0, r1, o1, c0, c1,
               ((kt + 2) & (DMODEL / 32 - 1)) * 32);
    asm volatile("s_waitcnt vmcnt(4)" ::: "memory");
    __builtin_amdgcn_s_barrier();
    __builtin_amdgcn_sched_barrier(0);
    GCOMP(As + 4096, Bs + 4096);
    __builtin_amdgcn_sched_barrier(0);
    __builtin_amdgcn_s_barrier();
  }
#undef GCOMP
}

// QKV projection: C[m,n] = x[m,:] . Wqkv[n,:]; scatter to q/k/vt, q pre-scaled.
__global__ __launch_bounds__(256, 3) void qkv_gemm(
    const u16* __restrict__ xb, const u16* __restrict__ wb,
    u16* __restrict__ qb, u16* __restrict__ kb, u16* __restrict__ vtb) {
  __shared__ u16 As[2 * 128 * 32];
  __shared__ u16 Bs[2 * 128 * 32];
  f32x4 acc[4][4];
#pragma unroll
  for (int i = 0; i < 4; ++i)
#pragma unroll
    for (int j = 0; j < 4; ++j) acc[i][j] = (f32x4){0.f, 0.f, 0.f, 0.f};
  gemm128_mainloop(xb + (size_t)blockIdx.y * 128 * DMODEL,
                   wb + (size_t)blockIdx.x * 128 * DMODEL, As, Bs, acc);
  const int lane = threadIdx.x & 63, w = threadIdx.x >> 6;
  const int rowg = lane >> 4, col = lane & 15, wm = w >> 1, wn = w & 1;
#pragma unroll
  for (int i = 0; i < 4; ++i) {
#pragma unroll
    for (int j = 0; j < 4; ++j) {
#pragma unroll
      for (int r = 0; r < 4; ++r) {
        int m = blockIdx.y * 128 + wm * 64 + i * 16 + rowg * 4 + r;
        int n = blockIdx.x * 128 + wn * 64 + j * 16 + col;
        int b = m >> 11, t = m & (TT - 1);
        int s = n >> 10, h = (n >> 6) & 15, d = n & 63;
        int bh = b * NH + h;
        float v = acc[i][j][r];
        if (s == 0)      qb[((size_t)bh * TT + t) * DH + d] = f2bf(v * QSCALE);
        else if (s == 1) kb[((size_t)bh * TT + t) * DH + d] = f2bf(v);
        else             vtb[((size_t)bh * DH + d) * TT + t] = f2bf(v);
      }
    }
  }
}

// Output projection: out[m,n] = ob[m,:] . Wproj[n,:], f32 out.
__global__ __launch_bounds__(256, 3) void proj_gemm(
    const u16* __restrict__ ab, const u16* __restrict__ wb, float* __restrict__ out) {
  __shared__ u16 As[2 * 128 * 32];
  __shared__ u16 Bs[2 * 128 * 32];
  f32x4 acc[4][4];
#pragma unroll
  for (int i = 0; i < 4; ++i)
#pragma unroll
    for (int j = 0; j < 4; ++j) acc[i][j] = (f32x4){0.f, 0.f, 0.f, 0.f};
  gemm128_mainloop(ab + (size_t)blockIdx.y * 128 * DMODEL,
                   wb + (size_t)blockIdx.x * 128 * DMODEL, As, Bs, acc);
  const int lane = threadIdx.x & 63, w = threadIdx.x >> 6;
  const int rowg = lane >> 4, col = lane & 15, wm = w >> 1, wn = w & 1;
#pragma unroll
  for (int i = 0; i < 4; ++i) {
#pragma unroll
    for (int j = 0; j < 4; ++j) {
#pragma unroll
      for (int r = 0; r < 4; ++r) {
        int m = blockIdx.y * 128 + wm * 64 + i * 16 + rowg * 4 + r;
        int n = blockIdx.x * 128 + wn * 64 + j * 16 + col;
        out[(size_t)m * DMODEL + n] = acc[i][j][r];
      }
    }
  }
}

// ---------- Flash attention: r15 form (best measured): 4 waves x 32 q, 32x32x16, ----------
// ---------- in-reg P, KVB=128, counted vmcnt(8), bh-major grid (K/V L2-local).   ----------
static __device__ __forceinline__ void attn_stage(
    const u16* __restrict__ kbase, const u16* __restrict__ vbase,
    int kt, u16* KsSel, u16* VsSel, int tid) {
#pragma unroll
  for (int p = 0; p < 4; ++p) {
    int c = p * 256 + tid;
    int row = c >> 3;
    int bI = (c & 7) * 16;
    gload16(kbase + kt * (KVB * DH) + row * DH + ((bI ^ ((row & 7) << 4)) >> 1), KsSel + c * 8);
  }
#pragma unroll
  for (int p = 0; p < 4; ++p) {
    int c = p * 256 + tid;
    int d = c >> 4;
    int bI = (c & 15) * 16;
    gload16(vbase + (size_t)d * TT + kt * KVB + ((bI ^ ((d & 7) << 4)) >> 1), VsSel + c * 8);
  }
}

__global__ __launch_bounds__(256, 2) void attn_kernel(
    const u16* __restrict__ qb, const u16* __restrict__ kb,
    const u16* __restrict__ vtb, const unsigned char* __restrict__ mask,
    u16* __restrict__ ob) {
  __shared__ u16 SM[2][2][KVB * DH];
  __shared__ unsigned char maskb[TT];
  __shared__ u32 mflag;

  const int tid = threadIdx.x;
  const int lane = tid & 63, w = tid >> 6;
  const int col = lane & 31, h = lane >> 5;
  const int bh = blockIdx.x, qt = blockIdx.y;   // bh-major: XCD = bh % 8
  const int b = bh >> 4;

  if (tid == 0) mflag = 0;
  __syncthreads();

  {
    const u32* mg = reinterpret_cast<const u32*>(mask + (size_t)b * TT);
    u32 m0 = mg[tid * 2], m1 = mg[tid * 2 + 1];
    *reinterpret_cast<u32*>(maskb + tid * 8) = m0;
    *reinterpret_cast<u32*>(maskb + tid * 8 + 4) = m1;
    if (m0 | m1) atomicOr(&mflag, 1u << (tid >> 4));
  }

  const int qrow0 = qt * 128 + w * 32;
  const u16* qptr = qb + ((size_t)bh * TT + qrow0) * DH;
  bf16x8 aq[4];
#pragma unroll
  for (int dstep = 0; dstep < 4; ++dstep)
    aq[dstep] = *reinterpret_cast<const bf16x8*>(qptr + col * DH + dstep * 16 + h * 8);

  f32x16 acc[2];
#pragma unroll
  for (int df = 0; df < 2; ++df)
#pragma unroll
    for (int r = 0; r < 16; ++r) acc[df][r] = 0.f;
  float m_run = -1e30f, l_run = 0.f;

  const u16* kbase = kb + (size_t)bh * TT * DH;
  const u16* vbase = vtb + (size_t)bh * DH * TT;

  attn_stage(kbase, vbase, 0, SM[0][0], SM[0][1], tid);
  __syncthreads();
  const u32 fm = mflag;

#define ATILE(T, KS, VS)                                                              \
  do {                                                                                \
    const int t_ = (T);                                                               \
    f32x16 sc[4];                                                                     \
    _Pragma("unroll") for (int kf = 0; kf < 4; ++kf)                                  \
      _Pragma("unroll") for (int r = 0; r < 16; ++r) sc[kf][r] = 0.f;                 \
    _Pragma("unroll") for (int dstep = 0; dstep < 4; ++dstep) {                       \
      bf16x8 ak[4];                                                                   \
      _Pragma("unroll") for (int kf = 0; kf < 4; ++kf) {                              \
        int row = kf * 32 + col;                                                      \
        ak[kf] = *reinterpret_cast<const bf16x8*>(                                    \
            (KS) + row * DH + (((dstep * 32 + h * 16) ^ ((row & 7) << 4)) >> 1));     \
      }                                                                               \
      _Pragma("unroll") for (int kf = 0; kf < 4; ++kf)                                \
        sc[kf] = __builtin_amdgcn_mfma_f32_32x32x16_bf16(ak[kf], aq[dstep], sc[kf], 0, 0, 0); \
    }                                                                                 \
    if (fm & (1u << t_)) {                                                            \
      _Pragma("unroll") for (int kf = 0; kf < 4; ++kf)                                \
        _Pragma("unroll") for (int r = 0; r < 16; ++r) {                              \
          int key = kf * 32 + (r & 3) + 8 * (r >> 2) + 4 * h;                         \
          sc[kf][r] += maskb[t_ * KVB + key] ? -1e30f : 0.f;                          \
        }                                                                             \
    }                                                                                 \
    u32 P2[4][8];                                                                     \
    {                                                                                 \
      float mk0 = maxv16(sc[0]), mk1 = maxv16(sc[1]);                                 \
      float mk2 = maxv16(sc[2]), mk3 = maxv16(sc[3]);                                 \
      float mx = fmaxf(fmaxf(mk0, mk1), fmaxf(mk2, mk3));                             \
      mx = fmaxf(mx, __shfl_xor(mx, 32, 64));                                         \
      if (__any(mx > m_run + 8.0f)) {                                                 \
        float mn = fmaxf(m_run, mx);                                                  \
        float corr = fexp2(m_run - mn);                                               \
        m_run = mn;                                                                   \
        l_run *= corr;                                                                \
        _Pragma("unroll") for (int df = 0; df < 2; ++df)                              \
          _Pragma("unroll") for (int r = 0; r < 16; ++r) acc[df][r] *= corr;          \
      }                                                                               \
      const float mc = m_run;                                                         \
      float rs = 0.f;                                                                 \
      _Pragma("unroll") for (int kf = 0; kf < 4; ++kf) {                              \
        _Pragma("unroll") for (int i = 0; i < 8; ++i) {                               \
          float p0 = fexp2(sc[kf][2 * i] - mc);                                       \
          float p1 = fexp2(sc[kf][2 * i + 1] - mc);                                   \
          rs += p0 + p1;                                                              \
          P2[kf][i] = pk2bf(p0, p1);                                                  \
        }                                                                             \
      }                                                                               \
      rs += __shfl_xor(rs, 32, 64);                                                   \
      l_run += rs;                                                                    \
    }                                                                                 \
    __builtin_amdgcn_s_setprio(1);                                                    \
    _Pragma("unroll") for (int ksl = 0; ksl < 8; ++ksl) {                             \
      const int kf = ksl >> 1;                                                        \
      const int i0 = (ksl & 1) * 4;                                                   \
      u32 w0 = P2[kf][i0],     w2 = P2[kf][i0 + 2];                                   \
      u32 w1 = P2[kf][i0 + 1], w3 = P2[kf][i0 + 3];                                   \
      asm("v_permlane32_swap_b32 %0, %1" : "+v"(w0), "+v"(w2));                       \
      asm("v_permlane32_swap_b32 %0, %1" : "+v"(w1), "+v"(w3));                       \
      u32 bpw[4] = {w0, w1, w2, w3};                                                  \
      bf16x8 bp = __builtin_bit_cast(bf16x8, *reinterpret_cast<uint4*>(bpw));         \
      _Pragma("unroll") for (int df = 0; df < 2; ++df) {                              \
        int row = df * 32 + col;                                                      \
        bf16x8 av = *reinterpret_cast<const bf16x8*>(                                 \
            (VS) + row * KVB + (((ksl * 32 + h * 16) ^ ((row & 7) << 4)) >> 1));      \
        acc[df] = __builtin_amdgcn_mfma_f32_32x32x16_bf16(av, bp, acc[df], 0, 0, 0);  \
      }                                                                               \
    }                                                                                 \
    __builtin_amdgcn_s_setprio(0);                                                    \
  } while (0)

  for (int t = 0; t < TT / KVB; t += 2) {
    attn_stage(kbase, vbase, t + 1, SM[1][0], SM[1][1], tid);
    asm volatile("s_waitcnt vmcnt(8)" ::: "memory");
    __builtin_amdgcn_s_barrier();
    __builtin_amdgcn_sched_barrier(0);
    ATILE(t, SM[0][0], SM[0][1]);
    __builtin_amdgcn_sched_barrier(0);
    __builtin_amdgcn_s_barrier();
    attn_stage(kbase, vbase, (t + 2) & (TT / KVB - 1), SM[0][0], SM[0][1], tid);
    asm volatile("s_waitcnt vmcnt(8)" ::: "memory");
    __builtin_amdgcn_s_barrier();
    __builtin_amdgcn_sched_barrier(0);
    ATILE(t + 1, SM[1][0], SM[1][1]);
    __builtin_amdgcn_sched_barrier(0);
    __builtin_amdgcn_s_barrier();
  }
#undef ATILE

  asm volatile("s_waitcnt vmcnt(0)" ::: "memory");
  __builtin_amdgcn_s_barrier();

  u16* Ol = &SM[0][0][0];
  {
    float inv = 1.f / l_run;
    const int q = w * 32 + col;
    const int swzq = (q ^ (q >> 3)) & 7;
#pragma unroll
    for (int df = 0; df < 2; ++df) {
#pragma unroll
      for (int a = 0; a < 4; ++a) {
        uint2 pk;
        pk.x = pk2bf(acc[df][4 * a] * inv, acc[df][4 * a + 1] * inv);
        pk.y = pk2bf(acc[df][4 * a + 2] * inv, acc[df][4 * a + 3] * inv);
        int d2 = df * 64 + a * 16 + h * 8;
        int byte = q * 128 + (d2 ^ (swzq << 4));
        *reinterpret_cast<uint2*>(reinterpret_cast<char*>(Ol) + byte) = pk;
      }
    }
  }
  __syncthreads();
  {
    const int hh = bh & 15;
#pragma unroll
    for (int p = 0; p < 4; ++p) {
      int idx = p * 256 + tid;
      int q = idx >> 3, ch = idx & 7;
      int swzq = (q ^ (q >> 3)) & 7;
      uint4 v = *reinterpret_cast<const uint4*>(
          reinterpret_cast<const char*>(Ol) + q * 128 + ((ch * 16) ^ (swzq << 4)));
      size_t row = (size_t)(b * TT + qt * 128 + q);
      *reinterpret_cast<uint4*>(ob + row * DMODEL + hh * DH + ch * 8) = v;
    }
  }
}

extern "C" void kernel_launch(void* const* d_in, const int* in_sizes, int n_in,
                              void* d_out, int out_size, void* d_ws, size_t ws_size,
                              hipStream_t stream) {
  const float* x = (const float*)d_in[0];
  const unsigned char* mask = (const unsigned char*)d_in[1];
  const float* wqkv = (const float*)d_in[2];
  const float* wproj = (const float*)d_in[3];
  float* out = (float*)d_out;

  u16* xb     = (u16*)d_ws;
  u16* wqkvb  = xb    + (size_t)MM * DMODEL;
  u16* wprojb = wqkvb + (size_t)NQKV * DMODEL;
  u16* qb     = wprojb + (size_t)DMODEL * DMODEL;
  u16* kb     = qb + (size_t)MM * DMODEL;
  u16* vtb    = kb + (size_t)MM * DMODEL;
  u16* ob     = vtb + (size_t)MM * DMODEL;

  cvt_all<<<(N4X + N4W + N4P) / 256, 256, 0, stream>>>(x, wqkv, wproj, xb);
  qkv_gemm<<<dim3(NQKV / 128, MM / 128), 256, 0, stream>>>(xb, wqkvb, qb, kb, vtb);
  attn_kernel<<<dim3(BB * NH, TT / 128), 256, 0, stream>>>(qb, kb, vtb, mask, ob);
  proj_gemm<<<dim3(DMODEL / 128, MM / 128), 256, 0, stream>>>(ob, wprojb, out);
}

// Round 19
// 120.928 us; speedup vs baseline: 1.1097x; 1.0491x over previous
//
#include <hip/hip_runtime.h>
#include <hip/hip_bf16.h>

typedef unsigned short u16;
typedef unsigned int u32;
typedef __bf16 bf16x8 __attribute__((ext_vector_type(8)));
typedef float f32x4 __attribute__((ext_vector_type(4)));
typedef float f32x16 __attribute__((ext_vector_type(16)));

#define DMODEL 1024
#define NH 16
#define DH 64
#define BB 2
#define TT 2048
#define MM 4096   // BB*TT
#define NQKV 3072
#define KVB 128   // attention key-tile

// Q pre-scale: Dh^-0.5 * log2(e) -> scores land in log2 domain (P = v_exp_f32 direct)
#define QSCALE 0.18033688011112042f

static __device__ __forceinline__ u16 f2bf(float f) {
  u32 u = __float_as_uint(f);
  u = (u + 0x7FFFu + ((u >> 16) & 1u)) >> 16;  // RNE
  return (u16)u;
}

static __device__ __forceinline__ u32 pk2bf(float a, float b) {
  u16 ua = __builtin_bit_cast(u16, (__bf16)a);
  u16 ub = __builtin_bit_cast(u16, (__bf16)b);
  return (u32)ua | ((u32)ub << 16);
}

static __device__ __forceinline__ float fexp2(float x) {
#if __has_builtin(__builtin_amdgcn_exp2f)
  return __builtin_amdgcn_exp2f(x);
#else
  float r; asm("v_exp_f32 %0, %1" : "=v"(r) : "v"(x)); return r;
#endif
}

static __device__ __forceinline__ float max3f(float a, float b, float c) {
  return fmaxf(fmaxf(a, b), c);  // fuses to v_max3_f32
}

static __device__ __forceinline__ float maxv16(const f32x16& v) {
  float t0 = max3f(v[0], v[1], v[2]);
  float t1 = max3f(v[3], v[4], v[5]);
  float t2 = max3f(v[6], v[7], v[8]);
  float t3 = max3f(v[9], v[10], v[11]);
  float t4 = max3f(v[12], v[13], v[14]);
  return fmaxf(max3f(t0, t1, t2), max3f(t3, t4, v[15]));
}

static __device__ __forceinline__ void gload16(const u16* g, u16* l) {
  __builtin_amdgcn_global_load_lds(
      (const __attribute__((address_space(1))) void*)g,
      (__attribute__((address_space(3))) void*)l, 16, 0, 0);
}

// Fused f32->bf16 convert: x | wqkv | wproj (dst regions contiguous in ws).
#define N4X  (MM * DMODEL / 4)
#define N4W  (NQKV * DMODEL / 4)
#define N4P  (DMODEL * DMODEL / 4)
__global__ __launch_bounds__(256) void cvt_all(const float* __restrict__ x,
                                               const float* __restrict__ wqkv,
                                               const float* __restrict__ wproj,
                                               u16* __restrict__ dst) {
  int i = blockIdx.x * 256 + threadIdx.x;
  const float* src;
  int j = i;
  if (i < N4X) {
    src = x;
  } else if (i < N4X + N4W) {
    src = wqkv; j = i - N4X;
  } else {
    src = wproj; j = i - (N4X + N4W);
  }
  float4 v = reinterpret_cast<const float4*>(src)[j];
  ushort4 o;
  o.x = f2bf(v.x); o.y = f2bf(v.y); o.z = f2bf(v.z); o.w = f2bf(v.w);
  reinterpret_cast<ushort4*>(dst)[i] = o;
}

// ---------- GEMM: 128x128 tile, K=1024, counted-vmcnt pipeline (r12 form) ----------
static __device__ __forceinline__ void gemm_stage(
    const u16* __restrict__ A, const u16* __restrict__ B, u16* As, u16* Bs,
    int r0, int o0, int r1, int o1, int c0, int c1, int kcol) {
  gload16(A + (size_t)r0 * DMODEL + kcol + o0, As + c0 * 8);
  gload16(A + (size_t)r1 * DMODEL + kcol + o1, As + c1 * 8);
  gload16(B + (size_t)r0 * DMODEL + kcol + o0, Bs + c0 * 8);
  gload16(B + (size_t)r1 * DMODEL + kcol + o1, Bs + c1 * 8);
}

static __device__ __forceinline__ void gemm128_mainloop(
    const u16* __restrict__ Abase, const u16* __restrict__ Bbase,
    u16* As, u16* Bs, f32x4 (&acc)[4][4]) {
  const int tid = threadIdx.x;
  const int lane = tid & 63;
  const int w = tid >> 6;
  const int rowg = lane >> 4, col = lane & 15;
  const int wm = w >> 1, wn = w & 1;
  const int c0 = tid, c1 = tid + 256;
  const int r0 = c0 >> 2, o0 = (c0 & 3) * 8;
  const int r1 = c1 >> 2, o1 = (c1 & 3) * 8;

  gemm_stage(Abase, Bbase, As, Bs, r0, o0, r1, o1, c0, c1, 0);

#define GCOMP(AS, BS)                                                                 \
  {                                                                                   \
    bf16x8 af[4], bfr[4];                                                             \
    _Pragma("unroll") for (int i = 0; i < 4; ++i)                                     \
      af[i] = *reinterpret_cast<const bf16x8*>((AS) + (wm * 64 + i * 16 + col) * 32 + rowg * 8); \
    _Pragma("unroll") for (int j = 0; j < 4; ++j)                                     \
      bfr[j] = *reinterpret_cast<const bf16x8*>((BS) + (wn * 64 + j * 16 + col) * 32 + rowg * 8); \
    _Pragma("unroll") for (int i = 0; i < 4; ++i)                                     \
      _Pragma("unroll") for (int j = 0; j < 4; ++j)                                   \
        acc[i][j] = __builtin_amdgcn_mfma_f32_16x16x32_bf16(af[i], bfr[j], acc[i][j], 0, 0, 0); \
  }

  for (int kt = 0; kt < DMODEL / 32; kt += 2) {
    gemm_stage(Abase, Bbase, As + 4096, Bs + 4096, r0, o0, r1, o1, c0, c1,
               ((kt + 1) & (DMODEL / 32 - 1)) * 32);
    asm volatile("s_waitcnt vmcnt(4)" ::: "memory");
    __builtin_amdgcn_s_barrier();
    __builtin_amdgcn_sched_barrier(0);
    GCOMP(As, Bs);
    __builtin_amdgcn_sched_barrier(0);
    __builtin_amdgcn_s_barrier();
    gemm_stage(Abase, Bbase, As, Bs, r0, o0, r1, o1, c0, c1,
               ((kt + 2) & (DMODEL / 32 - 1)) * 32);
    asm volatile("s_waitcnt vmcnt(4)" ::: "memory");
    __builtin_amdgcn_s_barrier();
    __builtin_amdgcn_sched_barrier(0);
    GCOMP(As + 4096, Bs + 4096);
    __builtin_amdgcn_sched_barrier(0);
    __builtin_amdgcn_s_barrier();
  }
#undef GCOMP
}

// QKV projection: C[m,n] = x[m,:] . Wqkv[n,:]; scatter to q/k/vt, q pre-scaled.
// Epilogue: vtb fragment (4 consecutive t at fixed d) packed into one 8B uint2 store
// (was 16 scalar u16 stores scattered 4KB apart across lanes).
__global__ __launch_bounds__(256, 3) void qkv_gemm(
    const u16* __restrict__ xb, const u16* __restrict__ wb,
    u16* __restrict__ qb, u16* __restrict__ kb, u16* __restrict__ vtb) {
  __shared__ u16 As[2 * 128 * 32];
  __shared__ u16 Bs[2 * 128 * 32];
  f32x4 acc[4][4];
#pragma unroll
  for (int i = 0; i < 4; ++i)
#pragma unroll
    for (int j = 0; j < 4; ++j) acc[i][j] = (f32x4){0.f, 0.f, 0.f, 0.f};
  gemm128_mainloop(xb + (size_t)blockIdx.y * 128 * DMODEL,
                   wb + (size_t)blockIdx.x * 128 * DMODEL, As, Bs, acc);
  const int lane = threadIdx.x & 63, w = threadIdx.x >> 6;
  const int rowg = lane >> 4, col = lane & 15, wm = w >> 1, wn = w & 1;
#pragma unroll
  for (int i = 0; i < 4; ++i) {
    const int m0 = blockIdx.y * 128 + wm * 64 + i * 16 + rowg * 4;  // r=0 row
    const int b = m0 >> 11, t0 = m0 & (TT - 1);                     // same b for r=0..3
#pragma unroll
    for (int j = 0; j < 4; ++j) {
      const int n = blockIdx.x * 128 + wn * 64 + j * 16 + col;
      const int s = n >> 10, hh = (n >> 6) & 15, d = n & 63;
      const int bh = b * NH + hh;
      if (s == 2) {
        uint2 pk;
        pk.x = pk2bf(acc[i][j][0], acc[i][j][1]);
        pk.y = pk2bf(acc[i][j][2], acc[i][j][3]);
        *reinterpret_cast<uint2*>(vtb + ((size_t)bh * DH + d) * TT + t0) = pk;
      } else {
#pragma unroll
        for (int r = 0; r < 4; ++r) {
          float v = acc[i][j][r];
          if (s == 0) qb[((size_t)bh * TT + t0 + r) * DH + d] = f2bf(v * QSCALE);
          else        kb[((size_t)bh * TT + t0 + r) * DH + d] = f2bf(v);
        }
      }
    }
  }
}

// Output projection: out[m,n] = ob[m,:] . Wproj[n,:], f32 out.
__global__ __launch_bounds__(256, 3) void proj_gemm(
    const u16* __restrict__ ab, const u16* __restrict__ wb, float* __restrict__ out) {
  __shared__ u16 As[2 * 128 * 32];
  __shared__ u16 Bs[2 * 128 * 32];
  f32x4 acc[4][4];
#pragma unroll
  for (int i = 0; i < 4; ++i)
#pragma unroll
    for (int j = 0; j < 4; ++j) acc[i][j] = (f32x4){0.f, 0.f, 0.f, 0.f};
  gemm128_mainloop(ab + (size_t)blockIdx.y * 128 * DMODEL,
                   wb + (size_t)blockIdx.x * 128 * DMODEL, As, Bs, acc);
  const int lane = threadIdx.x & 63, w = threadIdx.x >> 6;
  const int rowg = lane >> 4, col = lane & 15, wm = w >> 1, wn = w & 1;
#pragma unroll
  for (int i = 0; i < 4; ++i) {
#pragma unroll
    for (int j = 0; j < 4; ++j) {
#pragma unroll
      for (int r = 0; r < 4; ++r) {
        int m = blockIdx.y * 128 + wm * 64 + i * 16 + rowg * 4 + r;
        int n = blockIdx.x * 128 + wn * 64 + j * 16 + col;
        out[(size_t)m * DMODEL + n] = acc[i][j][r];
      }
    }
  }
}

// ---------- Flash attention: r15 form (best measured): 4 waves x 32 q, 32x32x16, ----------
// ---------- in-reg P, KVB=128, counted vmcnt(8), bh-major grid (K/V L2-local).   ----------
static __device__ __forceinline__ void attn_stage(
    const u16* __restrict__ kbase, const u16* __restrict__ vbase,
    int kt, u16* KsSel, u16* VsSel, int tid) {
#pragma unroll
  for (int p = 0; p < 4; ++p) {
    int c = p * 256 + tid;
    int row = c >> 3;
    int bI = (c & 7) * 16;
    gload16(kbase + kt * (KVB * DH) + row * DH + ((bI ^ ((row & 7) << 4)) >> 1), KsSel + c * 8);
  }
#pragma unroll
  for (int p = 0; p < 4; ++p) {
    int c = p * 256 + tid;
    int d = c >> 4;
    int bI = (c & 15) * 16;
    gload16(vbase + (size_t)d * TT + kt * KVB + ((bI ^ ((d & 7) << 4)) >> 1), VsSel + c * 8);
  }
}

__global__ __launch_bounds__(256, 2) void attn_kernel(
    const u16* __restrict__ qb, const u16* __restrict__ kb,
    const u16* __restrict__ vtb, const unsigned char* __restrict__ mask,
    u16* __restrict__ ob) {
  __shared__ u16 SM[2][2][KVB * DH];
  __shared__ unsigned char maskb[TT];
  __shared__ u32 mflag;

  const int tid = threadIdx.x;
  const int lane = tid & 63, w = tid >> 6;
  const int col = lane & 31, h = lane >> 5;
  const int bh = blockIdx.x, qt = blockIdx.y;   // bh-major: XCD = bh % 8
  const int b = bh >> 4;

  if (tid == 0) mflag = 0;
  __syncthreads();

  {
    const u32* mg = reinterpret_cast<const u32*>(mask + (size_t)b * TT);
    u32 m0 = mg[tid * 2], m1 = mg[tid * 2 + 1];
    *reinterpret_cast<u32*>(maskb + tid * 8) = m0;
    *reinterpret_cast<u32*>(maskb + tid * 8 + 4) = m1;
    if (m0 | m1) atomicOr(&mflag, 1u << (tid >> 4));
  }

  const int qrow0 = qt * 128 + w * 32;
  const u16* qptr = qb + ((size_t)bh * TT + qrow0) * DH;
  bf16x8 aq[4];
#pragma unroll
  for (int dstep = 0; dstep < 4; ++dstep)
    aq[dstep] = *reinterpret_cast<const bf16x8*>(qptr + col * DH + dstep * 16 + h * 8);

  f32x16 acc[2];
#pragma unroll
  for (int df = 0; df < 2; ++df)
#pragma unroll
    for (int r = 0; r < 16; ++r) acc[df][r] = 0.f;
  float m_run = -1e30f, l_run = 0.f;

  const u16* kbase = kb + (size_t)bh * TT * DH;
  const u16* vbase = vtb + (size_t)bh * DH * TT;

  attn_stage(kbase, vbase, 0, SM[0][0], SM[0][1], tid);
  __syncthreads();
  const u32 fm = mflag;

#define ATILE(T, KS, VS)                                                              \
  do {                                                                                \
    const int t_ = (T);                                                               \
    f32x16 sc[4];                                                                     \
    _Pragma("unroll") for (int kf = 0; kf < 4; ++kf)                                  \
      _Pragma("unroll") for (int r = 0; r < 16; ++r) sc[kf][r] = 0.f;                 \
    _Pragma("unroll") for (int dstep = 0; dstep < 4; ++dstep) {                       \
      bf16x8 ak[4];                                                                   \
      _Pragma("unroll") for (int kf = 0; kf < 4; ++kf) {                              \
        int row = kf * 32 + col;                                                      \
        ak[kf] = *reinterpret_cast<const bf16x8*>(                                    \
            (KS) + row * DH + (((dstep * 32 + h * 16) ^ ((row & 7) << 4)) >> 1));     \
      }                                                                               \
      _Pragma("unroll") for (int kf = 0; kf < 4; ++kf)                                \
        sc[kf] = __builtin_amdgcn_mfma_f32_32x32x16_bf16(ak[kf], aq[dstep], sc[kf], 0, 0, 0); \
    }                                                                                 \
    if (fm & (1u << t_)) {                                                            \
      _Pragma("unroll") for (int kf = 0; kf < 4; ++kf)                                \
        _Pragma("unroll") for (int r = 0; r < 16; ++r) {                              \
          int key = kf * 32 + (r & 3) + 8 * (r >> 2) + 4 * h;                         \
          sc[kf][r] += maskb[t_ * KVB + key] ? -1e30f : 0.f;                          \
        }                                                                             \
    }                                                                                 \
    u32 P2[4][8];                                                                     \
    {                                                                                 \
      float mk0 = maxv16(sc[0]), mk1 = maxv16(sc[1]);                                 \
      float mk2 = maxv16(sc[2]), mk3 = maxv16(sc[3]);                                 \
      float mx = fmaxf(fmaxf(mk0, mk1), fmaxf(mk2, mk3));                             \
      mx = fmaxf(mx, __shfl_xor(mx, 32, 64));                                         \
      if (__any(mx > m_run + 8.0f)) {                                                 \
        float mn = fmaxf(m_run, mx);                                                  \
        float corr = fexp2(m_run - mn);                                               \
        m_run = mn;                                                                   \
        l_run *= corr;                                                                \
        _Pragma("unroll") for (int df = 0; df < 2; ++df)                              \
          _Pragma("unroll") for (int r = 0; r < 16; ++r) acc[df][r] *= corr;          \
      }                                                                               \
      const float mc = m_run;                                                         \
      float rs = 0.f;                                                                 \
      _Pragma("unroll") for (int kf = 0; kf < 4; ++kf) {                              \
        _Pragma("unroll") for (int i = 0; i < 8; ++i) {                               \
          float p0 = fexp2(sc[kf][2 * i] - mc);                                       \
          float p1 = fexp2(sc[kf][2 * i + 1] - mc);                                   \
          rs += p0 + p1;                                                              \
          P2[kf][i] = pk2bf(p0, p1);                                                  \
        }                                                                             \
      }                                                                               \
      rs += __shfl_xor(rs, 32, 64);                                                   \
      l_run += rs;                                                                    \
    }                                                                                 \
    __builtin_amdgcn_s_setprio(1);                                                    \
    _Pragma("unroll") for (int ksl = 0; ksl < 8; ++ksl) {                             \
      const int kf = ksl >> 1;                                                        \
      const int i0 = (ksl & 1) * 4;                                                   \
      u32 w0 = P2[kf][i0],     w2 = P2[kf][i0 + 2];                                   \
      u32 w1 = P2[kf][i0 + 1], w3 = P2[kf][i0 + 3];                                   \
      asm("v_permlane32_swap_b32 %0, %1" : "+v"(w0), "+v"(w2));                       \
      asm("v_permlane32_swap_b32 %0, %1" : "+v"(w1), "+v"(w3));                       \
      u32 bpw[4] = {w0, w1, w2, w3};                                                  \
      bf16x8 bp = __builtin_bit_cast(bf16x8, *reinterpret_cast<uint4*>(bpw));         \
      _Pragma("unroll") for (int df = 0; df < 2; ++df) {                              \
        int row = df * 32 + col;                                                      \
        bf16x8 av = *reinterpret_cast<const bf16x8*>(                                 \
            (VS) + row * KVB + (((ksl * 32 + h * 16) ^ ((row & 7) << 4)) >> 1));      \
        acc[df] = __builtin_amdgcn_mfma_f32_32x32x16_bf16(av, bp, acc[df], 0, 0, 0);  \
      }                                                                               \
    }                                                                                 \
    __builtin_amdgcn_s_setprio(0);                                                    \
  } while (0)

  for (int t = 0; t < TT / KVB; t += 2) {
    attn_stage(kbase, vbase, t + 1, SM[1][0], SM[1][1], tid);
    asm volatile("s_waitcnt vmcnt(8)" ::: "memory");
    __builtin_amdgcn_s_barrier();
    __builtin_amdgcn_sched_barrier(0);
    ATILE(t, SM[0][0], SM[0][1]);
    __builtin_amdgcn_sched_barrier(0);
    __builtin_amdgcn_s_barrier();
    attn_stage(kbase, vbase, (t + 2) & (TT / KVB - 1), SM[0][0], SM[0][1], tid);
    asm volatile("s_waitcnt vmcnt(8)" ::: "memory");
    __builtin_amdgcn_s_barrier();
    __builtin_amdgcn_sched_barrier(0);
    ATILE(t + 1, SM[1][0], SM[1][1]);
    __builtin_amdgcn_sched_barrier(0);
    __builtin_amdgcn_s_barrier();
  }
#undef ATILE

  asm volatile("s_waitcnt vmcnt(0)" ::: "memory");
  __builtin_amdgcn_s_barrier();

  u16* Ol = &SM[0][0][0];
  {
    float inv = 1.f / l_run;
    const int q = w * 32 + col;
    const int swzq = (q ^ (q >> 3)) & 7;
#pragma unroll
    for (int df = 0; df < 2; ++df) {
#pragma unroll
      for (int a = 0; a < 4; ++a) {
        uint2 pk;
        pk.x = pk2bf(acc[df][4 * a] * inv, acc[df][4 * a + 1] * inv);
        pk.y = pk2bf(acc[df][4 * a + 2] * inv, acc[df][4 * a + 3] * inv);
        int d2 = df * 64 + a * 16 + h * 8;
        int byte = q * 128 + (d2 ^ (swzq << 4));
        *reinterpret_cast<uint2*>(reinterpret_cast<char*>(Ol) + byte) = pk;
      }
    }
  }
  __syncthreads();
  {
    const int hh = bh & 15;
#pragma unroll
    for (int p = 0; p < 4; ++p) {
      int idx = p * 256 + tid;
      int q = idx >> 3, ch = idx & 7;
      int swzq = (q ^ (q >> 3)) & 7;
      uint4 v = *reinterpret_cast<const uint4*>(
          reinterpret_cast<const char*>(Ol) + q * 128 + ((ch * 16) ^ (swzq << 4)));
      size_t row = (size_t)(b * TT + qt * 128 + q);
      *reinterpret_cast<uint4*>(ob + row * DMODEL + hh * DH + ch * 8) = v;
    }
  }
}

extern "C" void kernel_launch(void* const* d_in, const int* in_sizes, int n_in,
                              void* d_out, int out_size, void* d_ws, size_t ws_size,
                              hipStream_t stream) {
  const float* x = (const float*)d_in[0];
  const unsigned char* mask = (const unsigned char*)d_in[1];
  const float* wqkv = (const float*)d_in[2];
  const float* wproj = (const float*)d_in[3];
  float* out = (float*)d_out;

  u16* xb     = (u16*)d_ws;
  u16* wqkvb  = xb    + (size_t)MM * DMODEL;
  u16* wprojb = wqkvb + (size_t)NQKV * DMODEL;
  u16* qb     = wprojb + (size_t)DMODEL * DMODEL;
  u16* kb     = qb + (size_t)MM * DMODEL;
  u16* vtb    = kb + (size_t)MM * DMODEL;
  u16* ob     = vtb + (size_t)MM * DMODEL;

  cvt_all<<<(N4X + N4W + N4P) / 256, 256, 0, stream>>>(x, wqkv, wproj, xb);
  qkv_gemm<<<dim3(NQKV / 128, MM / 128), 256, 0, stream>>>(xb, wqkvb, qb, kb, vtb);
  attn_kernel<<<dim3(BB * NH, TT / 128), 256, 0, stream>>>(qb, kb, vtb, mask, ob);
  proj_gemm<<<dim3(DMODEL / 128, MM / 128), 256, 0, stream>>>(ob, wprojb, out);
}